// Round 8
// baseline (506.795 us; speedup 1.0000x reference)
//
#include <hip/hip_runtime.h>

#define NN 100000
#define NE 1200000
#define NB_SCAN ((NN + 255) / 256)   // 391 blocks
#define NPASS 8
#define WNODES ((NN + NPASS - 1) / NPASS)   // 12500 nodes per scatter window
#define EB 128                               // blocks per scatter pass
#define GF_BLOCKS 64
#define WS_BLOCKS 1024

// ---------------- CSR build ----------------
__global__ void k_hist(const int* __restrict__ ei, int* __restrict__ cnt) {
    int i = blockIdx.x * 256 + threadIdx.x;
    if (i < NE) atomicAdd(&cnt[ei[NE + i]], 1);   // dst row
}

// colw[s] = sum over edges s->d of dinv[d]  (layer-3 column-sum weights)
__global__ void k_colw(const int* __restrict__ ei, const float* __restrict__ dinv,
                       float* __restrict__ colw) {
    int e = blockIdx.x * 256 + threadIdx.x;
    if (e < NE) atomicAdd(&colw[ei[e]], dinv[ei[NE + e]]);
}

// scan block + dinv fused (reads cnt anyway)
__global__ void k_scan_block(const int* __restrict__ cnt, int* __restrict__ incl,
                             int* __restrict__ bsum, float* __restrict__ dinv) {
    __shared__ int s[256];
    int t = threadIdx.x;
    int i = blockIdx.x * 256 + t;
    int v = (i < NN) ? cnt[i] : 0;
    if (i < NN) dinv[i] = rsqrtf((float)v + 1.0f);
    s[t] = v;
    __syncthreads();
    for (int off = 1; off < 256; off <<= 1) {
        int add = (t >= off) ? s[t - off] : 0;
        __syncthreads();
        s[t] += add;
        __syncthreads();
    }
    if (i < NN) incl[i] = s[t];
    if (t == 255) bsum[blockIdx.x] = s[255];
}

__global__ void k_scan_bsum(int* __restrict__ bsum) {
    __shared__ int s[512];
    int t = threadIdx.x;
    s[t] = (t < NB_SCAN) ? bsum[t] : 0;
    __syncthreads();
    for (int off = 1; off < 512; off <<= 1) {
        int add = (t >= off) ? s[t - off] : 0;
        __syncthreads();
        s[t] += add;
        __syncthreads();
    }
    if (t < NB_SCAN) bsum[t] = s[t];
}

__global__ void k_scan_add(const int* __restrict__ cnt, const int* __restrict__ incl,
                           const int* __restrict__ bsum, int* __restrict__ rowptr) {
    int i = blockIdx.x * 256 + threadIdx.x;
    if (i >= NN) return;
    int base = (blockIdx.x > 0) ? bsum[blockIdx.x - 1] : 0;
    rowptr[i] = base + incl[i] - cnt[i];   // exclusive scan
    if (i == 0) rowptr[NN] = NE;
}

// XCD-affine windowed scatter: window = blockIdx % 8 so (round-robin
// dispatch heuristic) all blocks of a window run on one XCD -> window's
// srcs lines live in that XCD's L2. Locality heuristic only; atomics
// guarantee correctness under any block->XCD mapping.
__global__ void k_scatter_win(const int* __restrict__ ei, const int* __restrict__ rowptr,
                              int* __restrict__ cursor, int* __restrict__ srcs) {
    int pass = blockIdx.x & (NPASS - 1);
    int blk  = blockIdx.x / NPASS;
    int lo = pass * WNODES;
    int hi = lo + WNODES;   // window 7 covers the tail (NN < 8*12500)
    for (int e = blk * 256 + threadIdx.x; e < NE; e += EB * 256) {
        int dst = ei[NE + e];
        if (dst >= lo && dst < hi) {
            int pos = rowptr[dst] + atomicAdd(&cursor[dst], 1);
            srcs[pos] = ei[e];
        }
    }
}

// ---------------- layer 1: aggregate x (5-wide) BEFORE matmul ----------------
__global__ void k_aggx(const int* __restrict__ rowptr, const int* __restrict__ srcs,
                       const float* __restrict__ dinv, const float* __restrict__ x,
                       float* __restrict__ aggx) {
    int t = threadIdx.x;
    int n = blockIdx.x * 4 + (t >> 6);
    if (n >= NN) return;
    int lane = t & 63, c = lane & 7, slot = lane >> 3;
    int e0 = rowptr[n], e1 = rowptr[n + 1];
    float es = 0.f;
    if (c < 5) {
        for (int j = e0 + slot; j < e1; j += 8) {
            int s = srcs[j];
            es += x[(size_t)s * 5 + c] * dinv[s];
        }
    }
    es += __shfl_xor(es, 8, 64);
    es += __shfl_xor(es, 16, 64);
    es += __shfl_xor(es, 32, 64);
    float dvn = dinv[n];
    if (slot == 0 && c < 5)
        aggx[(size_t)n * 5 + c] = es * dvn + x[(size_t)n * 5 + c] * dvn * dvn;
}

// (N,5) @ (5,64) + b, relu -> h1
__global__ void k_lin_first(const float* __restrict__ aggx, const float* __restrict__ W,
                            const float* __restrict__ b, float* __restrict__ h) {
    __shared__ float Ws[5 * 64];
    __shared__ float bs[64];
    int t = threadIdx.x;
    for (int i = t; i < 320; i += 256) Ws[i] = W[i];
    if (t < 64) bs[t] = b[t];
    __syncthreads();
    int r = t >> 6, c = t & 63;
    int row = blockIdx.x * 4 + r;
    if (row >= NN) return;
    float acc = bs[c];
#pragma unroll
    for (int k = 0; k < 5; k++) acc += aggx[(size_t)row * 5 + k] * Ws[k * 64 + c];
    h[(size_t)row * 64 + c] = fmaxf(acc, 0.f);
}

// ---------------- 64->64 matmul ----------------
__global__ void k_lin64(const float* __restrict__ in, const float* __restrict__ W,
                        float* __restrict__ h) {
    __shared__ float Ws[64 * 64];
    __shared__ float rows[256];
    int t = threadIdx.x;
    for (int i = t; i < 4096; i += 256) Ws[i] = W[i];
    int base = blockIdx.x * 4;
    int gidx = base * 64 + t;
    rows[t] = (gidx < NN * 64) ? in[gidx] : 0.f;
    __syncthreads();
    int r = t >> 6, c = t & 63, row = base + r;
    if (row >= NN) return;
    float acc = 0.f;
#pragma unroll
    for (int k = 0; k < 64; k++) acc += rows[r * 64 + k] * Ws[k * 64 + c];
    h[(size_t)row * 64 + c] = acc;
}

// ---------------- pull aggregation (64-wide), 4-way unrolled edge loop ----------------
template <bool RELU>
__global__ void k_agg64(const int* __restrict__ rowptr, const int* __restrict__ srcs,
                        const float* __restrict__ dinv, const float* __restrict__ h,
                        const float* __restrict__ b, float* __restrict__ out) {
    int t = threadIdx.x;
    int n = blockIdx.x * 4 + (t >> 6);
    if (n >= NN) return;
    int c = t & 63;
    int e0 = rowptr[n], e1 = rowptr[n + 1];
    float dvn = dinv[n];
    float acc0 = 0.f, acc1 = 0.f, acc2 = 0.f, acc3 = 0.f;
    int j = e0;
    for (; j + 3 < e1; j += 4) {
        int s0 = srcs[j], s1 = srcs[j + 1], s2 = srcs[j + 2], s3 = srcs[j + 3];
        float w0 = dinv[s0], w1 = dinv[s1], w2 = dinv[s2], w3 = dinv[s3];
        acc0 += h[(size_t)s0 * 64 + c] * w0;
        acc1 += h[(size_t)s1 * 64 + c] * w1;
        acc2 += h[(size_t)s2 * 64 + c] * w2;
        acc3 += h[(size_t)s3 * 64 + c] * w3;
    }
    for (; j < e1; j++) {
        int s0 = srcs[j];
        acc0 += h[(size_t)s0 * 64 + c] * dinv[s0];
    }
    float v = ((acc0 + acc1) + (acc2 + acc3)) * dvn
            + h[(size_t)n * 64 + c] * dvn * dvn + b[c];
    if (RELU) v = fmaxf(v, 0.f);
    out[(size_t)n * 64 + c] = v;
}

// ---------------- layer-3: weighted column-sum of h2 (streaming, coalesced) ----------------
// m[c] = sum_s dinv[s]*(colw[s]+dinv[s]) * h2[s][c]   -> per-block partials
__global__ void k_wsum(const float* __restrict__ h2, const float* __restrict__ colw,
                       const float* __restrict__ dinv, float* __restrict__ part) {
    int t = threadIdx.x;
    int c = t & 63;
    float acc = 0.f;
    for (int r = blockIdx.x * 4 + (t >> 6); r < NN; r += WS_BLOCKS * 4) {
        float dv = dinv[r];
        acc += dv * (colw[r] + dv) * h2[(size_t)r * 64 + c];
    }
    __shared__ float s[256];
    s[t] = acc;
    __syncthreads();
    if (t < 128) s[t] += s[t + 128];
    __syncthreads();
    if (t < 64) part[blockIdx.x * 64 + t] = s[t] + s[t + 64];
}

// ---------------- global-feature partials (no atomics) ----------------
__global__ void k_gf_part(const float* __restrict__ x, float* __restrict__ gfpart) {
    int t = threadIdx.x;
    float sc = 0, sa = 0, so = 0, sl = 0, sm = 0;
    for (int i = blockIdx.x * 256 + t; i < NN; i += gridDim.x * 256) {
        float lam = x[i * 5 + 0], mu = x[i * 5 + 1];
        float c = x[i * 5 + 2], a = x[i * 5 + 3], o = x[i * 5 + 4];
        sc += c; sa += a; so += o; sl += lam * c; sm += mu * c;
    }
    __shared__ float s[256];
    float vals[5] = {sc, sa, so, sl, sm};
#pragma unroll
    for (int k = 0; k < 5; k++) {
        s[t] = vals[k];
        __syncthreads();
        for (int off = 128; off > 0; off >>= 1) {
            if (t < off) s[t] += s[t + off];
            __syncthreads();
        }
        if (t == 0) gfpart[blockIdx.x * 5 + k] = s[0];
        __syncthreads();
    }
}

// ---------------- final reduce + W3 matvec + MLP (1 block, 256 threads) ----------------
__device__ __forceinline__ float softplus_f(float x) {
    return (x > 20.f) ? x : log1pf(expf(x));
}

__global__ void k_mlp(const float* __restrict__ part64, const float* __restrict__ gfpart,
                      const float* __restrict__ W3, const float* __restrict__ b3,
                      const float* __restrict__ T, const float* __restrict__ Tmax,
                      const float* __restrict__ P1, const float* __restrict__ pb1,
                      const float* __restrict__ P2, const float* __restrict__ pb2,
                      const float* __restrict__ P3, const float* __restrict__ pb3,
                      float* __restrict__ out) {
    __shared__ float s[256];
    __shared__ float m[64];
    __shared__ float emb[24];
    __shared__ float hm1[64];
    __shared__ float hm2[32];
    __shared__ float val[4];
    int t = threadIdx.x;
    // reduce part64 (WS_BLOCKS x 64): c = t&63, group g = t>>6 sums strided rows
    {
        int c = t & 63, g = t >> 6;
        float acc = 0.f;
        for (int r = g; r < WS_BLOCKS; r += 4) acc += part64[r * 64 + c];
        s[t] = acc;
        __syncthreads();
        if (t < 128) s[t] += s[t + 128];
        __syncthreads();
        if (t < 64) m[t] = s[t] + s[t + 64];
        __syncthreads();
    }
    // emb[0..15] = m @ W3 / N + b3
    if (t < 16) {
        float acc = 0.f;
#pragma unroll
        for (int c = 0; c < 64; c++) acc += m[c] * W3[c * 16 + t];
        emb[t] = acc / (float)NN + b3[t];
    }
    // reduce gfpart (GF_BLOCKS x 5)
    if (t >= 32 && t < 37) {
        int k = t - 32;
        float acc = 0.f;
        for (int r = 0; r < GF_BLOCKS; r++) acc += gfpart[r * 5 + k];
        s[k] = acc;
    }
    __syncthreads();
    if (t == 0) {
        float sc = s[0], sa = s[1], so = s[2], sl = s[3], sm = s[4];
        float Tn = T[0] / Tmax[0];
        emb[16] = sc;
        emb[17] = sa;
        emb[18] = so;
        emb[19] = sa + so;
        float safe = fmaxf(sc, 1.0f);
        bool has = sc > 0.f;
        emb[20] = has ? sl / safe : 0.f;
        emb[21] = has ? sm / safe : 0.f;
        emb[22] = Tn * 50.f;
        emb[23] = (1.f / (1.f + Tn)) * 50.f;
    }
    __syncthreads();
    if (t < 64) {
        float acc = pb1[t];
#pragma unroll
        for (int k = 0; k < 24; k++) acc += emb[k] * P1[k * 64 + t];
        hm1[t] = fmaxf(acc, 0.f);
    }
    __syncthreads();
    if (t < 32) {
        float acc = pb2[t];
#pragma unroll
        for (int k = 0; k < 64; k++) acc += hm1[k] * P2[k * 32 + t];
        hm2[t] = fmaxf(acc, 0.f);
    }
    __syncthreads();
    if (t < 4) {
        float acc = pb3[t];
#pragma unroll
        for (int k = 0; k < 32; k++) acc += hm2[k] * P3[k * 4 + t];
        val[t] = softplus_f(acc + 2.0f);
    }
    __syncthreads();
    if (t == 0) {
        float amin = 1.f + val[0];
        float amax = amin + val[1] + 0.5f;
        float bmin = 1.f + val[2];
        float bmax = bmin + val[3] + 0.5f;
        out[0] = amin; out[1] = amax; out[2] = bmin; out[3] = bmax;
    }
    if (t >= 4 && t < 28) out[t] = emb[t - 4];
}

extern "C" void kernel_launch(void* const* d_in, const int* in_sizes, int n_in,
                              void* d_out, int out_size, void* d_ws, size_t ws_size,
                              hipStream_t stream) {
    const float* x    = (const float*)d_in[0];
    const int*   ei   = (const int*)d_in[1];
    const float* T    = (const float*)d_in[2];
    const float* Tmax = (const float*)d_in[3];
    const float* W1   = (const float*)d_in[4];
    const float* b1   = (const float*)d_in[5];
    const float* W2   = (const float*)d_in[6];
    const float* b2   = (const float*)d_in[7];
    const float* W3   = (const float*)d_in[8];
    const float* b3   = (const float*)d_in[9];
    const float* P1   = (const float*)d_in[10];
    const float* pb1  = (const float*)d_in[11];
    const float* P2   = (const float*)d_in[12];
    const float* pb2  = (const float*)d_in[13];
    const float* P3   = (const float*)d_in[14];
    const float* pb3  = (const float*)d_in[15];
    float* out = (float*)d_out;

    // workspace carve-up (cnt, cursor, colw contiguous -> one memset)
    char* w = (char*)d_ws;
    float* bufH   = (float*)w;                 w += (size_t)NN * 64 * 4;
    float* bufA   = (float*)w;                 w += (size_t)NN * 64 * 4;
    int*   cnt    = (int*)w;                   w += (size_t)NN * 4;
    int*   cursor = (int*)w;                   w += (size_t)NN * 4;
    float* colw   = (float*)w;                 w += (size_t)NN * 4;
    float* dinv   = (float*)w;                 w += (size_t)NN * 4;
    int*   incl   = (int*)w;                   w += (size_t)NN * 4;
    int*   rowptr = (int*)w;                   w += (size_t)(NN + 1) * 4;
    int*   srcs   = (int*)w;                   w += (size_t)NE * 4;
    int*   bsum   = (int*)w;                   w += 512 * 4;
    float* aggx   = (float*)w;                 w += (size_t)NN * 5 * 4;
    float* part64 = (float*)w;                 w += (size_t)WS_BLOCKS * 64 * 4;
    float* gfpart = (float*)w;                 w += (size_t)GF_BLOCKS * 5 * 4;

    hipMemsetAsync(cnt, 0, 3 * (size_t)NN * sizeof(int), stream);

    // CSR build (by dst) + dinv + colw
    k_hist<<<(NE + 255) / 256, 256, 0, stream>>>(ei, cnt);
    k_scan_block<<<NB_SCAN, 256, 0, stream>>>(cnt, incl, bsum, dinv);
    k_scan_bsum<<<1, 512, 0, stream>>>(bsum);
    k_scan_add<<<NB_SCAN, 256, 0, stream>>>(cnt, incl, bsum, rowptr);
    k_scatter_win<<<NPASS * EB, 256, 0, stream>>>(ei, rowptr, cursor, srcs);
    k_colw<<<(NE + 255) / 256, 256, 0, stream>>>(ei, dinv, colw);

    // layer 1 (commuted: aggregate 5-wide x first, then matmul+bias+relu)
    k_aggx<<<(NN + 3) / 4, 256, 0, stream>>>(rowptr, srcs, dinv, x, aggx);
    k_lin_first<<<(NN + 3) / 4, 256, 0, stream>>>(aggx, W1, b1, bufA);

    // layer 2
    k_lin64<<<(NN + 3) / 4, 256, 0, stream>>>(bufA, W2, bufH);
    k_agg64<true><<<(NN + 3) / 4, 256, 0, stream>>>(rowptr, srcs, dinv, bufH, b2, bufA);

    // layer 3: emb = (colsum-weighted sum of h2) @ W3 / N + b3  (no gather!)
    k_wsum<<<WS_BLOCKS, 256, 0, stream>>>(bufA, colw, dinv, part64);

    // global features + final reduce/MLP
    k_gf_part<<<GF_BLOCKS, 256, 0, stream>>>(x, gfpart);
    k_mlp<<<1, 256, 0, stream>>>(part64, gfpart, W3, b3, T, Tmax,
                                 P1, pb1, P2, pb2, P3, pb3, out);
}

// Round 9
// 470.595 us; speedup vs baseline: 1.0769x; 1.0769x over previous
//
#include <hip/hip_runtime.h>

#define NN 100000
#define NE 1200000
#define NB_SCAN ((NN + 255) / 256)   // 391 blocks
#define NPASS 8
#define WNODES ((NN + NPASS - 1) / NPASS)   // 12500 nodes per scatter window
#define EB 128                               // blocks per scatter pass
#define GF_BLOCKS 64
#define WS_BLOCKS 256

// ---------------- CSR build ----------------
__global__ void k_hist(const int* __restrict__ ei, int* __restrict__ cnt) {
    int i = blockIdx.x * 256 + threadIdx.x;
    if (i < NE) atomicAdd(&cnt[ei[NE + i]], 1);   // dst row
}

// colw[s] = sum over edges s->d of dinv[d]  (layer-3 column-sum weights)
__global__ void k_colw(const int* __restrict__ ei, const float* __restrict__ dinv,
                       float* __restrict__ colw) {
    int e = blockIdx.x * 256 + threadIdx.x;
    if (e < NE) atomicAdd(&colw[ei[e]], dinv[ei[NE + e]]);
}

// scan block + dinv fused (reads cnt anyway)
__global__ void k_scan_block(const int* __restrict__ cnt, int* __restrict__ incl,
                             int* __restrict__ bsum, float* __restrict__ dinv) {
    __shared__ int s[256];
    int t = threadIdx.x;
    int i = blockIdx.x * 256 + t;
    int v = (i < NN) ? cnt[i] : 0;
    if (i < NN) dinv[i] = rsqrtf((float)v + 1.0f);
    s[t] = v;
    __syncthreads();
    for (int off = 1; off < 256; off <<= 1) {
        int add = (t >= off) ? s[t - off] : 0;
        __syncthreads();
        s[t] += add;
        __syncthreads();
    }
    if (i < NN) incl[i] = s[t];
    if (t == 255) bsum[blockIdx.x] = s[255];
}

__global__ void k_scan_bsum(int* __restrict__ bsum) {
    __shared__ int s[512];
    int t = threadIdx.x;
    s[t] = (t < NB_SCAN) ? bsum[t] : 0;
    __syncthreads();
    for (int off = 1; off < 512; off <<= 1) {
        int add = (t >= off) ? s[t - off] : 0;
        __syncthreads();
        s[t] += add;
        __syncthreads();
    }
    if (t < NB_SCAN) bsum[t] = s[t];
}

__global__ void k_scan_add(const int* __restrict__ cnt, const int* __restrict__ incl,
                           const int* __restrict__ bsum, int* __restrict__ rowptr) {
    int i = blockIdx.x * 256 + threadIdx.x;
    if (i >= NN) return;
    int base = (blockIdx.x > 0) ? bsum[blockIdx.x - 1] : 0;
    rowptr[i] = base + incl[i] - cnt[i];   // exclusive scan
    if (i == 0) rowptr[NN] = NE;
}

// XCD-affine windowed scatter (window = blockIdx % 8; locality heuristic only)
__global__ void k_scatter_win(const int* __restrict__ ei, const int* __restrict__ rowptr,
                              int* __restrict__ cursor, int* __restrict__ srcs) {
    int pass = blockIdx.x & (NPASS - 1);
    int blk  = blockIdx.x / NPASS;
    int lo = pass * WNODES;
    int hi = lo + WNODES;   // window 7 covers the tail (NN < 8*12500)
    for (int e = blk * 256 + threadIdx.x; e < NE; e += EB * 256) {
        int dst = ei[NE + e];
        if (dst >= lo && dst < hi) {
            int pos = rowptr[dst] + atomicAdd(&cursor[dst], 1);
            srcs[pos] = ei[e];
        }
    }
}

// ---------------- layer 1: aggregate x (5-wide) BEFORE matmul ----------------
__global__ void k_aggx(const int* __restrict__ rowptr, const int* __restrict__ srcs,
                       const float* __restrict__ dinv, const float* __restrict__ x,
                       float* __restrict__ aggx) {
    int t = threadIdx.x;
    int n = blockIdx.x * 4 + (t >> 6);
    if (n >= NN) return;
    int lane = t & 63, c = lane & 7, slot = lane >> 3;
    int e0 = rowptr[n], e1 = rowptr[n + 1];
    float es = 0.f;
    if (c < 5) {
        for (int j = e0 + slot; j < e1; j += 8) {
            int s = srcs[j];
            es += x[(size_t)s * 5 + c] * dinv[s];
        }
    }
    es += __shfl_xor(es, 8, 64);
    es += __shfl_xor(es, 16, 64);
    es += __shfl_xor(es, 32, 64);
    float dvn = dinv[n];
    if (slot == 0 && c < 5)
        aggx[(size_t)n * 5 + c] = es * dvn + x[(size_t)n * 5 + c] * dvn * dvn;
}

// (N,5) @ (5,64) + b, relu -> h1
__global__ void k_lin_first(const float* __restrict__ aggx, const float* __restrict__ W,
                            const float* __restrict__ b, float* __restrict__ h) {
    __shared__ float Ws[5 * 64];
    __shared__ float bs[64];
    int t = threadIdx.x;
    for (int i = t; i < 320; i += 256) Ws[i] = W[i];
    if (t < 64) bs[t] = b[t];
    __syncthreads();
    int r = t >> 6, c = t & 63;
    int row = blockIdx.x * 4 + r;
    if (row >= NN) return;
    float acc = bs[c];
#pragma unroll
    for (int k = 0; k < 5; k++) acc += aggx[(size_t)row * 5 + k] * Ws[k * 64 + c];
    h[(size_t)row * 64 + c] = fmaxf(acc, 0.f);
}

// ---------------- 64->64 matmul ----------------
__global__ void k_lin64(const float* __restrict__ in, const float* __restrict__ W,
                        float* __restrict__ h) {
    __shared__ float Ws[64 * 64];
    __shared__ float rows[256];
    int t = threadIdx.x;
    for (int i = t; i < 4096; i += 256) Ws[i] = W[i];
    int base = blockIdx.x * 4;
    int gidx = base * 64 + t;
    rows[t] = (gidx < NN * 64) ? in[gidx] : 0.f;
    __syncthreads();
    int r = t >> 6, c = t & 63, row = base + r;
    if (row >= NN) return;
    float acc = 0.f;
#pragma unroll
    for (int k = 0; k < 64; k++) acc += rows[r * 64 + k] * Ws[k * 64 + c];
    h[(size_t)row * 64 + c] = acc;
}

// ---------------- pull aggregation (64-wide), 4-way unrolled edge loop ----------------
template <bool RELU>
__global__ void k_agg64(const int* __restrict__ rowptr, const int* __restrict__ srcs,
                        const float* __restrict__ dinv, const float* __restrict__ h,
                        const float* __restrict__ b, float* __restrict__ out) {
    int t = threadIdx.x;
    int n = blockIdx.x * 4 + (t >> 6);
    if (n >= NN) return;
    int c = t & 63;
    int e0 = rowptr[n], e1 = rowptr[n + 1];
    float dvn = dinv[n];
    float acc0 = 0.f, acc1 = 0.f, acc2 = 0.f, acc3 = 0.f;
    int j = e0;
    for (; j + 3 < e1; j += 4) {
        int s0 = srcs[j], s1 = srcs[j + 1], s2 = srcs[j + 2], s3 = srcs[j + 3];
        float w0 = dinv[s0], w1 = dinv[s1], w2 = dinv[s2], w3 = dinv[s3];
        acc0 += h[(size_t)s0 * 64 + c] * w0;
        acc1 += h[(size_t)s1 * 64 + c] * w1;
        acc2 += h[(size_t)s2 * 64 + c] * w2;
        acc3 += h[(size_t)s3 * 64 + c] * w3;
    }
    for (; j < e1; j++) {
        int s0 = srcs[j];
        acc0 += h[(size_t)s0 * 64 + c] * dinv[s0];
    }
    float v = ((acc0 + acc1) + (acc2 + acc3)) * dvn
            + h[(size_t)n * 64 + c] * dvn * dvn + b[c];
    if (RELU) v = fmaxf(v, 0.f);
    out[(size_t)n * 64 + c] = v;
}

// ---------------- layer-3: weighted column-sum of h2 (streaming, coalesced) ----------------
// m[c] = sum_s dinv[s]*(colw[s]+dinv[s]) * h2[s][c]   -> per-block partials
__global__ void k_wsum(const float* __restrict__ h2, const float* __restrict__ colw,
                       const float* __restrict__ dinv, float* __restrict__ part) {
    int t = threadIdx.x;
    int c = t & 63;
    float acc = 0.f;
    for (int r = blockIdx.x * 4 + (t >> 6); r < NN; r += WS_BLOCKS * 4) {
        float dv = dinv[r];
        acc += dv * (colw[r] + dv) * h2[(size_t)r * 64 + c];
    }
    __shared__ float s[256];
    s[t] = acc;
    __syncthreads();
    if (t < 128) s[t] += s[t + 128];
    __syncthreads();
    if (t < 64) part[blockIdx.x * 64 + t] = s[t] + s[t + 64];
}

// ---------------- global-feature partials (no atomics) ----------------
__global__ void k_gf_part(const float* __restrict__ x, float* __restrict__ gfpart) {
    int t = threadIdx.x;
    float sc = 0, sa = 0, so = 0, sl = 0, sm = 0;
    for (int i = blockIdx.x * 256 + t; i < NN; i += gridDim.x * 256) {
        float lam = x[i * 5 + 0], mu = x[i * 5 + 1];
        float c = x[i * 5 + 2], a = x[i * 5 + 3], o = x[i * 5 + 4];
        sc += c; sa += a; so += o; sl += lam * c; sm += mu * c;
    }
    __shared__ float s[256];
    float vals[5] = {sc, sa, so, sl, sm};
#pragma unroll
    for (int k = 0; k < 5; k++) {
        s[t] = vals[k];
        __syncthreads();
        for (int off = 128; off > 0; off >>= 1) {
            if (t < off) s[t] += s[t + off];
            __syncthreads();
        }
        if (t == 0) gfpart[blockIdx.x * 5 + k] = s[0];
        __syncthreads();
    }
}

// ---------------- final reduce + W3 matvec + MLP (1 block, 256 threads) ----------------
__device__ __forceinline__ float softplus_f(float x) {
    return (x > 20.f) ? x : log1pf(expf(x));
}

__global__ void k_mlp(const float* __restrict__ part64, const float* __restrict__ gfpart,
                      const float* __restrict__ W3, const float* __restrict__ b3,
                      const float* __restrict__ T, const float* __restrict__ Tmax,
                      const float* __restrict__ P1, const float* __restrict__ pb1,
                      const float* __restrict__ P2, const float* __restrict__ pb2,
                      const float* __restrict__ P3, const float* __restrict__ pb3,
                      float* __restrict__ out) {
    __shared__ float sf[256][4];
    __shared__ float Ws3[64 * 16];
    __shared__ float gfs[GF_BLOCKS][5];
    __shared__ float m[64];
    __shared__ float emb[24];
    __shared__ float hm1[64];
    __shared__ float hm2[32];
    __shared__ float val[4];
    int t = threadIdx.x;

    // stage W3 into LDS (coalesced, all threads)
    for (int i = t; i < 1024; i += 256) Ws3[i] = W3[i];
    // stage gfpart into LDS (threads 0..63, one row each; 5 scalars)
    if (t < GF_BLOCKS) {
#pragma unroll
        for (int k = 0; k < 5; k++) gfs[t][k] = gfpart[t * 5 + k];
    }

    // reduce part64 (WS_BLOCKS x 64) as float4: f4col = t&15 (fixed), 16 rows/thread
    {
        const float4* p4 = (const float4*)part64;
        int f4c = t & 15, g = t >> 4;
        float4 a = make_float4(0.f, 0.f, 0.f, 0.f);
#pragma unroll
        for (int k = 0; k < WS_BLOCKS / 16; k++) {
            float4 v = p4[(g + k * 16) * 16 + f4c];
            a.x += v.x; a.y += v.y; a.z += v.z; a.w += v.w;
        }
        sf[t][0] = a.x; sf[t][1] = a.y; sf[t][2] = a.z; sf[t][3] = a.w;
        __syncthreads();
        for (int off = 128; off >= 16; off >>= 1) {
            if (t < off) {
#pragma unroll
                for (int j = 0; j < 4; j++) sf[t][j] += sf[t + off][j];
            }
            __syncthreads();
        }
        if (t < 16) {
#pragma unroll
            for (int j = 0; j < 4; j++) m[t * 4 + j] = sf[t][j];
        }
        __syncthreads();
    }
    // emb[0..15] = m @ W3 / N + b3  (W3 from LDS)
    if (t < 16) {
        float acc = 0.f;
#pragma unroll
        for (int c = 0; c < 64; c++) acc += m[c] * Ws3[c * 16 + t];
        emb[t] = acc / (float)NN + b3[t];
    }
    // reduce gfpart columns (threads 32..36, LDS reads)
    if (t >= 32 && t < 37) {
        int k = t - 32;
        float acc = 0.f;
        for (int r = 0; r < GF_BLOCKS; r++) acc += gfs[r][k];
        sf[0][0 * 0];   // no-op to keep sf live
        gfs[0][k] = acc;  // store column sums in row 0
    }
    __syncthreads();
    if (t == 0) {
        float sc = gfs[0][0], sa = gfs[0][1], so = gfs[0][2], sl = gfs[0][3], sm = gfs[0][4];
        float Tn = T[0] / Tmax[0];
        emb[16] = sc;
        emb[17] = sa;
        emb[18] = so;
        emb[19] = sa + so;
        float safe = fmaxf(sc, 1.0f);
        bool has = sc > 0.f;
        emb[20] = has ? sl / safe : 0.f;
        emb[21] = has ? sm / safe : 0.f;
        emb[22] = Tn * 50.f;
        emb[23] = (1.f / (1.f + Tn)) * 50.f;
    }
    __syncthreads();
    if (t < 64) {
        float acc = pb1[t];
#pragma unroll
        for (int k = 0; k < 24; k++) acc += emb[k] * P1[k * 64 + t];
        hm1[t] = fmaxf(acc, 0.f);
    }
    __syncthreads();
    if (t < 32) {
        float acc = pb2[t];
#pragma unroll
        for (int k = 0; k < 64; k++) acc += hm1[k] * P2[k * 32 + t];
        hm2[t] = fmaxf(acc, 0.f);
    }
    __syncthreads();
    if (t < 4) {
        float acc = pb3[t];
#pragma unroll
        for (int k = 0; k < 32; k++) acc += hm2[k] * P3[k * 4 + t];
        val[t] = softplus_f(acc + 2.0f);
    }
    __syncthreads();
    if (t == 0) {
        float amin = 1.f + val[0];
        float amax = amin + val[1] + 0.5f;
        float bmin = 1.f + val[2];
        float bmax = bmin + val[3] + 0.5f;
        out[0] = amin; out[1] = amax; out[2] = bmin; out[3] = bmax;
    }
    if (t >= 4 && t < 28) out[t] = emb[t - 4];
}

extern "C" void kernel_launch(void* const* d_in, const int* in_sizes, int n_in,
                              void* d_out, int out_size, void* d_ws, size_t ws_size,
                              hipStream_t stream) {
    const float* x    = (const float*)d_in[0];
    const int*   ei   = (const int*)d_in[1];
    const float* T    = (const float*)d_in[2];
    const float* Tmax = (const float*)d_in[3];
    const float* W1   = (const float*)d_in[4];
    const float* b1   = (const float*)d_in[5];
    const float* W2   = (const float*)d_in[6];
    const float* b2   = (const float*)d_in[7];
    const float* W3   = (const float*)d_in[8];
    const float* b3   = (const float*)d_in[9];
    const float* P1   = (const float*)d_in[10];
    const float* pb1  = (const float*)d_in[11];
    const float* P2   = (const float*)d_in[12];
    const float* pb2  = (const float*)d_in[13];
    const float* P3   = (const float*)d_in[14];
    const float* pb3  = (const float*)d_in[15];
    float* out = (float*)d_out;

    // workspace carve-up (cnt, cursor, colw contiguous -> one memset)
    char* w = (char*)d_ws;
    float* bufH   = (float*)w;                 w += (size_t)NN * 64 * 4;
    float* bufA   = (float*)w;                 w += (size_t)NN * 64 * 4;
    int*   cnt    = (int*)w;                   w += (size_t)NN * 4;
    int*   cursor = (int*)w;                   w += (size_t)NN * 4;
    float* colw   = (float*)w;                 w += (size_t)NN * 4;
    float* dinv   = (float*)w;                 w += (size_t)NN * 4;
    int*   incl   = (int*)w;                   w += (size_t)NN * 4;
    int*   rowptr = (int*)w;                   w += (size_t)(NN + 1) * 4;
    int*   srcs   = (int*)w;                   w += (size_t)NE * 4;
    int*   bsum   = (int*)w;                   w += 512 * 4;
    float* aggx   = (float*)w;                 w += (size_t)NN * 5 * 4;
    w = (char*)(((size_t)w + 15) & ~(size_t)15);           // float4 alignment
    float* part64 = (float*)w;                 w += (size_t)WS_BLOCKS * 64 * 4;
    float* gfpart = (float*)w;                 w += (size_t)GF_BLOCKS * 5 * 4;

    hipMemsetAsync(cnt, 0, 3 * (size_t)NN * sizeof(int), stream);

    // CSR build (by dst) + dinv + colw
    k_hist<<<(NE + 255) / 256, 256, 0, stream>>>(ei, cnt);
    k_scan_block<<<NB_SCAN, 256, 0, stream>>>(cnt, incl, bsum, dinv);
    k_scan_bsum<<<1, 512, 0, stream>>>(bsum);
    k_scan_add<<<NB_SCAN, 256, 0, stream>>>(cnt, incl, bsum, rowptr);
    k_scatter_win<<<NPASS * EB, 256, 0, stream>>>(ei, rowptr, cursor, srcs);
    k_colw<<<(NE + 255) / 256, 256, 0, stream>>>(ei, dinv, colw);

    // layer 1 (commuted: aggregate 5-wide x first, then matmul+bias+relu)
    k_aggx<<<(NN + 3) / 4, 256, 0, stream>>>(rowptr, srcs, dinv, x, aggx);
    k_lin_first<<<(NN + 3) / 4, 256, 0, stream>>>(aggx, W1, b1, bufA);

    // layer 2
    k_lin64<<<(NN + 3) / 4, 256, 0, stream>>>(bufA, W2, bufH);
    k_agg64<true><<<(NN + 3) / 4, 256, 0, stream>>>(rowptr, srcs, dinv, bufH, b2, bufA);

    // layer 3: emb = (colsum-weighted sum of h2) @ W3 / N + b3  (no gather!)
    k_wsum<<<WS_BLOCKS, 256, 0, stream>>>(bufA, colw, dinv, part64);

    // global features + final reduce/MLP
    k_gf_part<<<GF_BLOCKS, 256, 0, stream>>>(x, gfpart);
    k_mlp<<<1, 256, 0, stream>>>(part64, gfpart, W3, b3, T, Tmax,
                                 P1, pb1, P2, pb2, P3, pb3, out);
}